// Round 8
// baseline (491.825 us; speedup 1.0000x reference)
//
#include <hip/hip_runtime.h>
#include <stdint.h>

// Problem constants (from reference) — all inputs/outputs are FP32.
#define T_DIM 16
#define M_DIM 1024
#define N_NODES 10000
#define NB 100
#define N_IN 8000
#define KI 4096             // i dimension (4*M)
#define KP 8192             // interleaved i' = 2*i + o (memory-contiguous axis of weight)
#define CHUNKS 16
#define I_CHUNK (KI / CHUNKS)        // 256 i-values per chunk
#define M_CHUNK (I_CHUNK / 4)        // 64 m-values per chunk
#define PITCH (I_CHUNK + 4)          // 260 shorts row pitch
#define TILES 625                    // 10000 nodes / 16 per tile, exact
#define SLAB (N_NODES * T_DIM * 2)   // 320000 floats per chunk-slab

typedef short short8 __attribute__((ext_vector_type(8)));
typedef float f32x4 __attribute__((ext_vector_type(4)));

// HW packed fp32->bf16 (RNE): low16 = cvt(a), high16 = cvt(b).
__device__ __forceinline__ unsigned int cvtpk(float a, float b) {
    unsigned int r;
    asm("v_cvt_pk_bf16_f32 %0, %1, %2" : "=v"(r) : "v"(a), "v"(b));
    return r;
}

// ---------------------------------------------------------------------------
// GEMM over ALL nodes: f[n,t,o] = sum_i x_out[t,i] * W[n,i,o]
// (fp32 in, fp32 acc, bf16 MFMA). K' = 8192 interleaved (i,o).
// ROUND 7 (resubmitted unchanged after acquisition timeout): dedup DROPPED.
// r4-r6 evidence: three structurally different B-paths (scatter, pipelined
// scatter, coalesced LDS) all landed at 461-469 µs total -> the
// referenced-only optimization and the scatter pattern were never the
// lever. Processing all 10000 nodes makes every weight access exactly
// sequential (the 16 concurrent chunk-blocks of a tile-group jointly cover
// each node's 32 KB contiguously), removes one dispatch + the counter/list
// dependency, and needs no indirection.
// B staging: per node, one fully-coalesced 1 KB global load (64 lanes x
// 16 B), packed to bf16 (cvtpk), stored to a per-wave LDS buffer with a
// per-row XOR-16 swizzle -> both the ds_write and the 16-col ds_read_b128
// are bank-conflict-free (guideline 21: same involution on both sides).
// LDS: 32 KB B + 8.3 KB x = 40.5 KB/block -> 3 blocks/CU, 12 waves/CU.
// grid = (157 tile-groups, 16 K-chunks) x 256 threads (4 waves, 1 tile each).
// ---------------------------------------------------------------------------
__global__ __launch_bounds__(256) void gemm_kernel(
    const float* __restrict__ x,       // fp32 [16][3][1024]
    const float* __restrict__ weight,  // fp32 [10000][4096][2]
    float* __restrict__ fws)           // fp32 [16][10000][16][2] partial slabs
{
    __shared__ unsigned short lds_x[T_DIM * PITCH];   // x_out chunk as bf16
    __shared__ unsigned short lds_b[4][16 * 256];     // per-wave B: 16 nodes x 256 k' bf16

    const int tid = threadIdx.x;
    const int chunk = blockIdx.y;

    // Stage this chunk's x_out[t, i] into LDS as bf16.
    // x_out[t, 4m + {0,1,2,3}] = [x[t,0,m], x[t,2,m], x[t,2,m], x[t,1,m]]
    for (int q = tid; q < T_DIM * M_CHUNK; q += 256) {
        int t = q >> 6;            // M_CHUNK == 64 per t
        int mloc = q & 63;
        int m = chunk * M_CHUNK + mloc;
        const float* xb = x + t * 3 * M_DIM + m;
        float v0 = xb[0];
        float v1 = xb[M_DIM];
        float v2 = xb[2 * M_DIM];
        unsigned int w0 = cvtpk(v0, v2);     // slots 4m+0, 4m+1
        unsigned int w1 = cvtpk(v2, v1);     // slots 4m+2, 4m+3
        *(uint2*)&lds_x[t * PITCH + mloc * 4] = make_uint2(w0, w1);
    }
    __syncthreads();

    const int wave = tid >> 6;
    const int lane = tid & 63;
    const int tile = blockIdx.x * 4 + wave;
    if (tile >= TILES) return;                // tail waves of last block

    const int col = lane & 15;   // n-slot within tile (B/C col)
    const int quad = lane >> 4;  // k-group
    const int n = tile * 16 + col;            // direct: no list indirection

    const size_t koff = (size_t)chunk * (KP / CHUNKS);  // k' base of this chunk
    // A source: 4 consecutive bf16 x_out values for t = lane&15.
    const unsigned short* xrow = &lds_x[(lane & 15) * PITCH + quad * 4];
    char* bb = (char*)lds_b[wave];

    f32x4 acc0 = {0.f, 0.f, 0.f, 0.f};
    f32x4 acc1 = {0.f, 0.f, 0.f, 0.f};

    // Two sub-steps of 256 k' each (16 MFMA k-steps total per chunk).
    #pragma unroll
    for (int s = 0; s < 2; ++s) {
        // --- Stage: per node, one fully-coalesced 1 KB load (256 k' fp32)
        //     from a SEQUENTIAL address (node = tile*16+nd), packed to bf16,
        //     written 8 B/lane with XOR-16 row swizzle (conflict-free).
        #pragma unroll
        for (int nd = 0; nd < 16; ++nd) {
            const float* src =
                weight + (size_t)(tile * 16 + nd) * KP + koff + s * 256 + lane * 4;
            f32x4 w4 = *(const f32x4*)src;
            unsigned int u0 = cvtpk(w4[0], w4[1]);
            unsigned int u1 = cvtpk(w4[2], w4[3]);
            *(uint2*)(bb + nd * 512 + ((lane * 8) ^ ((nd & 7) << 4))) =
                make_uint2(u0, u1);
        }
        // (wave-private LDS region: same-wave DS ordering via lgkmcnt —
        //  compiler inserts the waits; no __syncthreads needed.)

        // --- Compute: 8 MFMA k-steps over the staged 256 k'.
        #pragma unroll
        for (int gs = 0; gs < 8; ++gs) {
            // B fragment: bf16 k' = gs*32 + quad*8 .. +7 of node `col`.
            // Same XOR-16 involution as the write side; 16-aligned.
            short8 Bv = *(const short8*)(
                bb + col * 512 + (((gs * 64 + quad * 16)) ^ ((col & 7) << 4)));

            int S = s * 8 + gs;
            uint2 u = *(const uint2*)(xrow + S * 16);
            union { unsigned int ui[4]; short8 v; } A0u, A1u;
            A0u.ui[0] = u.x & 0xFFFFu;      A0u.ui[1] = u.x >> 16;
            A0u.ui[2] = u.y & 0xFFFFu;      A0u.ui[3] = u.y >> 16;
            A1u.ui[0] = u.x << 16;          A1u.ui[1] = u.x & 0xFFFF0000u;
            A1u.ui[2] = u.y << 16;          A1u.ui[3] = u.y & 0xFFFF0000u;

            acc0 = __builtin_amdgcn_mfma_f32_16x16x32_bf16(A0u.v, Bv, acc0, 0, 0, 0);
            acc1 = __builtin_amdgcn_mfma_f32_16x16x32_bf16(A1u.v, Bv, acc1, 0, 0, 0);
        }
    }

    // C/D layout: col = lane&15, row(t) = quad*4 + reg.
    // Plain float2 stores into this chunk's slab (each addr written once).
    float* slab = fws + (size_t)chunk * SLAB;
    #pragma unroll
    for (int r = 0; r < 4; ++r) {
        int t = quad * 4 + r;
        *(float2*)&slab[((size_t)n * T_DIM + t) * 2] = make_float2(acc0[r], acc1[r]);
    }
}

// ---------------------------------------------------------------------------
// Gather f_in = f[node_in-1] (256000 fp32, float4-vectorized: 8 threads/node)
// + boundary sums f_b (96 fp32). f = sum of the 16 chunk slabs (LLC-resident).
// ---------------------------------------------------------------------------
__global__ __launch_bounds__(256) void gather_kernel(
    const float* __restrict__ fws,
    const int* __restrict__ node_in,
    const int* __restrict__ top, const int* __restrict__ bottom,
    const int* __restrict__ left, const int* __restrict__ right,
    float* __restrict__ out)
{
    const int tid = threadIdx.x;
    if (blockIdx.x < 250) {
        int e4 = blockIdx.x * 1024 + tid * 4;  // element base; 256000 = 250*1024
        int j = e4 >> 5;                       // node_in index (32 elems/node)
        int rem = e4 & 31;                     // (t*2+o) base, 16B aligned
        size_t base = (size_t)(node_in[j] - 1) * 32 + rem;
        float4 v = {0.f, 0.f, 0.f, 0.f};
        #pragma unroll
        for (int c = 0; c < CHUNKS; ++c) {
            float4 s = *(const float4*)&fws[c * (size_t)SLAB + base];
            v.x += s.x; v.y += s.y; v.z += s.z; v.w += s.w;
        }
        *(float4*)&out[e4] = v;
    } else {
        __shared__ float red[256];
        __shared__ float sums[64];
        const int l = tid >> 6;                // 0=top 1=bottom 2=left 3=right
        const int t = (tid >> 2) & 15;
        const int p = tid & 3;
        // Select chain instead of runtime-indexed pointer array (rule #20).
        const int* lp = (l == 0) ? top : (l == 1) ? bottom : (l == 2) ? left : right;
        const int osel = (l < 2) ? 1 : 0;
        float s = 0.f;
        for (int idx = p; idx < NB; idx += 4) {
            size_t base = (size_t)(lp[idx] - 1) * 32 + t * 2 + osel;
            #pragma unroll
            for (int c = 0; c < CHUNKS; ++c) s += fws[c * (size_t)SLAB + base];
        }
        red[tid] = s;
        __syncthreads();
        if (p == 0)
            sums[tid >> 2] = red[tid] + red[tid + 1] + red[tid + 2] + red[tid + 3];
        __syncthreads();
        if (tid < 96) {
            int row = tid >> 4;                // 0..5 -> [top,bot,left,right,t+b,l+r]
            int tt = tid & 15;
            float v;
            if (row < 4)       v = sums[row * 16 + tt];
            else if (row == 4) v = sums[0 * 16 + tt] + sums[1 * 16 + tt];
            else               v = sums[2 * 16 + tt] + sums[3 * 16 + tt];
            out[256000 + tid] = v;
        }
    }
}

extern "C" void kernel_launch(void* const* d_in, const int* in_sizes, int n_in,
                              void* d_out, int out_size, void* d_ws, size_t ws_size,
                              hipStream_t stream)
{
    const float* x      = (const float*)d_in[0];
    const float* weight = (const float*)d_in[1];
    const int* node_in = (const int*)d_in[2];
    const int* top     = (const int*)d_in[3];
    const int* bottom  = (const int*)d_in[4];
    const int* left    = (const int*)d_in[5];
    const int* right   = (const int*)d_in[6];

    float* fws = (float*)d_ws;                 // 16 slabs x 1.28 MB = 20.5 MB
    float* out = (float*)d_out;                // 256000 f_in + 96 f_b

    dim3 grid((TILES + 3) / 4, CHUNKS);        // 157 x 16
    gemm_kernel<<<grid, 256, 0, stream>>>(x, weight, fws);
    gather_kernel<<<251, 256, 0, stream>>>(fws, node_in, top, bottom, left, right, out);
}

// Round 10
// 461.162 us; speedup vs baseline: 1.0665x; 1.0665x over previous
//
#include <hip/hip_runtime.h>
#include <stdint.h>

// Problem constants (from reference) — all inputs/outputs are FP32.
#define T_DIM 16
#define M_DIM 1024
#define N_NODES 10000
#define NB 100
#define N_IN 8000
#define KI 4096             // i dimension (4*M)
#define KP 8192             // interleaved i' = 2*i + o (memory-contiguous axis of weight)
#define CHUNKS 16
#define I_CHUNK (KI / CHUNKS)        // 256 i-values per chunk
#define M_CHUNK (I_CHUNK / 4)        // 64 m-values per chunk
#define PITCH (I_CHUNK + 4)          // 260 shorts row pitch
#define TILES 625                    // worst-case tiles over all 10000 nodes
#define SLAB (N_NODES * T_DIM * 2)   // 320000 floats per chunk-slab

typedef short short8 __attribute__((ext_vector_type(8)));
typedef float f32x4 __attribute__((ext_vector_type(4)));

// HW packed fp32->bf16 (RNE): low16 = cvt(a), high16 = cvt(b).
__device__ __forceinline__ unsigned int cvtpk(float a, float b) {
    unsigned int r;
    asm("v_cvt_pk_bf16_f32 %0, %1, %2" : "=v"(r) : "v"(a), "v"(b));
    return r;
}

// ---------------------------------------------------------------------------
// Dedup: flag all referenced nodes in LDS, compact into a dense id list.
// r8 proved the gemm is HBM-streaming-bound (marginal 4.6 TB/s), so the
// 187 MB (dedup) vs 328 MB (all-nodes) traffic difference is worth ~30 µs
// — dedup restored. Ballot compaction; list comes out piecewise-sorted.
// ---------------------------------------------------------------------------
__global__ __launch_bounds__(1024) void dedup_kernel(
    const int* __restrict__ node_in,
    const int* __restrict__ top, const int* __restrict__ bottom,
    const int* __restrict__ left, const int* __restrict__ right,
    int* __restrict__ counter, int* __restrict__ list)
{
    __shared__ int flags[N_NODES];       // 40 KB
    __shared__ int lcnt;
    const int tid = threadIdx.x;
    for (int i = tid; i < N_NODES; i += 1024) flags[i] = 0;
    if (tid == 0) lcnt = 0;
    __syncthreads();
    for (int i = tid; i < N_IN + 4 * NB; i += 1024) {
        int v;
        if (i < N_IN)              v = node_in[i];
        else if (i < N_IN + NB)    v = top[i - N_IN];
        else if (i < N_IN + 2*NB)  v = bottom[i - N_IN - NB];
        else if (i < N_IN + 3*NB)  v = left[i - N_IN - 2*NB];
        else                       v = right[i - N_IN - 3*NB];
        flags[v - 1] = 1;
    }
    __syncthreads();
    const int lane = tid & 63;
    for (int i = tid; i < N_NODES; i += 1024) {
        int f = flags[i];
        unsigned long long mask = __ballot(f);
        int prefix = __popcll(mask & ((1ull << lane) - 1ull));
        int base = 0;
        if (lane == 0) base = atomicAdd(&lcnt, (int)__popcll(mask));
        base = __shfl(base, 0);
        if (f) list[base + prefix] = i;
    }
    __syncthreads();
    if (tid == 0) *counter = lcnt;
}

// ---------------------------------------------------------------------------
// GEMM over REFERENCED nodes only: f[n,t,o] = sum_i x_out[t,i] * W[n,i,o]
// (fp32 in, fp32 acc, bf16 MFMA). K' = 8192 interleaved (i,o).
// BEST-OF MERGE (r6 structure + r8-verified swizzle): referenced-only
// traffic (187 MB — the r8 all-nodes experiment showed the gemm streams at
// ~4.6 TB/s marginal, so traffic is the cost) with the B path staged
// through LDS via per-node fully-coalesced 1 KB loads (64 lanes x 16 B of
// ONE node), cvtpk to bf16, and an XOR-16 row swizzle applied on BOTH the
// ds_write and the ds_read_b128 (same involution -> conflict-free both
// sides, guideline 21; correctness harness-verified in r8).
// LDS: 32 KB B + 8.3 KB x = 40.5 KB/block -> 3 blocks/CU, 12 waves/CU.
// grid = (157 tile-groups, 16 K-chunks) x 256 threads (4 waves, 1 tile each);
// blocks fully past the compacted count exit before staging.
// ---------------------------------------------------------------------------
__global__ __launch_bounds__(256) void gemm_kernel(
    const float* __restrict__ x,       // fp32 [16][3][1024]
    const float* __restrict__ weight,  // fp32 [10000][4096][2]
    const int* __restrict__ list,      // compacted referenced node ids
    const int* __restrict__ counter,   // number of referenced nodes
    float* __restrict__ fws)           // fp32 [16][10000][16][2] partial slabs
{
    __shared__ unsigned short lds_x[T_DIM * PITCH];   // x_out chunk as bf16
    __shared__ unsigned short lds_b[4][16 * 256];     // per-wave B: 16 nodes x 256 k' bf16

    const int tid = threadIdx.x;
    const int chunk = blockIdx.y;

    const int cnt = *counter;                 // block-uniform scalar
    if (blockIdx.x * 64 >= cnt) return;       // whole block unneeded (4 waves x 16)

    // Stage this chunk's x_out[t, i] into LDS as bf16.
    // x_out[t, 4m + {0,1,2,3}] = [x[t,0,m], x[t,2,m], x[t,2,m], x[t,1,m]]
    for (int q = tid; q < T_DIM * M_CHUNK; q += 256) {
        int t = q >> 6;            // M_CHUNK == 64 per t
        int mloc = q & 63;
        int m = chunk * M_CHUNK + mloc;
        const float* xb = x + t * 3 * M_DIM + m;
        float v0 = xb[0];
        float v1 = xb[M_DIM];
        float v2 = xb[2 * M_DIM];
        unsigned int w0 = cvtpk(v0, v2);     // slots 4m+0, 4m+1
        unsigned int w1 = cvtpk(v2, v1);     // slots 4m+2, 4m+3
        *(uint2*)&lds_x[t * PITCH + mloc * 4] = make_uint2(w0, w1);
    }
    __syncthreads();

    const int wave = tid >> 6;
    const int lane = tid & 63;
    const int tile = blockIdx.x * 4 + wave;
    if (tile * 16 >= cnt) return;             // whole wave unneeded

    const int col = lane & 15;   // n-slot within tile (B/C col)
    const int quad = lane >> 4;  // k-group
    const int idx = tile * 16 + col;
    const int n = (idx < cnt) ? list[idx] : 0;

    const size_t koff = (size_t)chunk * (KP / CHUNKS);  // k' base of this chunk
    // A source: 4 consecutive bf16 x_out values for t = lane&15.
    const unsigned short* xrow = &lds_x[(lane & 15) * PITCH + quad * 4];
    char* bb = (char*)lds_b[wave];

    f32x4 acc0 = {0.f, 0.f, 0.f, 0.f};
    f32x4 acc1 = {0.f, 0.f, 0.f, 0.f};

    // Two sub-steps of 256 k' each (16 MFMA k-steps total per chunk).
    #pragma unroll
    for (int s = 0; s < 2; ++s) {
        // --- Stage: per node, one fully-coalesced 1 KB load (256 k' fp32),
        //     packed to bf16, written 8 B/lane with XOR-16 swizzle.
        #pragma unroll
        for (int nd = 0; nd < 16; ++nd) {
            int nn = __shfl(n, nd);          // node id held by lane nd
            const float* src =
                weight + (size_t)nn * KP + koff + s * 256 + lane * 4;
            f32x4 w4 = *(const f32x4*)src;
            unsigned int u0 = cvtpk(w4[0], w4[1]);
            unsigned int u1 = cvtpk(w4[2], w4[3]);
            *(uint2*)(bb + nd * 512 + ((lane * 8) ^ ((nd & 7) << 4))) =
                make_uint2(u0, u1);
        }
        // (wave-private LDS region: same-wave DS ordering via lgkmcnt —
        //  compiler inserts the waits; no __syncthreads needed.)

        // --- Compute: 8 MFMA k-steps over the staged 256 k'.
        #pragma unroll
        for (int gs = 0; gs < 8; ++gs) {
            // B fragment: bf16 k' = gs*32 + quad*8 .. +7 of node `col`.
            // Same XOR-16 involution as the write side; 16-aligned.
            short8 Bv = *(const short8*)(
                bb + col * 512 + ((gs * 64 + quad * 16) ^ ((col & 7) << 4)));

            int S = s * 8 + gs;
            uint2 u = *(const uint2*)(xrow + S * 16);
            union { unsigned int ui[4]; short8 v; } A0u, A1u;
            A0u.ui[0] = u.x & 0xFFFFu;      A0u.ui[1] = u.x >> 16;
            A0u.ui[2] = u.y & 0xFFFFu;      A0u.ui[3] = u.y >> 16;
            A1u.ui[0] = u.x << 16;          A1u.ui[1] = u.x & 0xFFFF0000u;
            A1u.ui[2] = u.y << 16;          A1u.ui[3] = u.y & 0xFFFF0000u;

            acc0 = __builtin_amdgcn_mfma_f32_16x16x32_bf16(A0u.v, Bv, acc0, 0, 0, 0);
            acc1 = __builtin_amdgcn_mfma_f32_16x16x32_bf16(A1u.v, Bv, acc1, 0, 0, 0);
        }
    }

    // C/D layout: col = lane&15, row(t) = quad*4 + reg.
    // Plain float2 stores into this chunk's slab (each addr written once;
    // padding lanes duplicate node 0 with identical values — benign).
    float* slab = fws + (size_t)chunk * SLAB;
    #pragma unroll
    for (int r = 0; r < 4; ++r) {
        int t = quad * 4 + r;
        *(float2*)&slab[((size_t)n * T_DIM + t) * 2] = make_float2(acc0[r], acc1[r]);
    }
}

// ---------------------------------------------------------------------------
// Gather f_in = f[node_in-1] (256000 fp32, float4-vectorized: 8 threads/node)
// + boundary sums f_b (96 fp32). f = sum of the 16 chunk slabs (LLC-resident).
// ---------------------------------------------------------------------------
__global__ __launch_bounds__(256) void gather_kernel(
    const float* __restrict__ fws,
    const int* __restrict__ node_in,
    const int* __restrict__ top, const int* __restrict__ bottom,
    const int* __restrict__ left, const int* __restrict__ right,
    float* __restrict__ out)
{
    const int tid = threadIdx.x;
    if (blockIdx.x < 250) {
        int e4 = blockIdx.x * 1024 + tid * 4;  // element base; 256000 = 250*1024
        int j = e4 >> 5;                       // node_in index (32 elems/node)
        int rem = e4 & 31;                     // (t*2+o) base, 16B aligned
        size_t base = (size_t)(node_in[j] - 1) * 32 + rem;
        float4 v = {0.f, 0.f, 0.f, 0.f};
        #pragma unroll
        for (int c = 0; c < CHUNKS; ++c) {
            float4 s = *(const float4*)&fws[c * (size_t)SLAB + base];
            v.x += s.x; v.y += s.y; v.z += s.z; v.w += s.w;
        }
        *(float4*)&out[e4] = v;
    } else {
        __shared__ float red[256];
        __shared__ float sums[64];
        const int l = tid >> 6;                // 0=top 1=bottom 2=left 3=right
        const int t = (tid >> 2) & 15;
        const int p = tid & 3;
        // Select chain instead of runtime-indexed pointer array (rule #20).
        const int* lp = (l == 0) ? top : (l == 1) ? bottom : (l == 2) ? left : right;
        const int osel = (l < 2) ? 1 : 0;
        float s = 0.f;
        for (int idx = p; idx < NB; idx += 4) {
            size_t base = (size_t)(lp[idx] - 1) * 32 + t * 2 + osel;
            #pragma unroll
            for (int c = 0; c < CHUNKS; ++c) s += fws[c * (size_t)SLAB + base];
        }
        red[tid] = s;
        __syncthreads();
        if (p == 0)
            sums[tid >> 2] = red[tid] + red[tid + 1] + red[tid + 2] + red[tid + 3];
        __syncthreads();
        if (tid < 96) {
            int row = tid >> 4;                // 0..5 -> [top,bot,left,right,t+b,l+r]
            int tt = tid & 15;
            float v;
            if (row < 4)       v = sums[row * 16 + tt];
            else if (row == 4) v = sums[0 * 16 + tt] + sums[1 * 16 + tt];
            else               v = sums[2 * 16 + tt] + sums[3 * 16 + tt];
            out[256000 + tid] = v;
        }
    }
}

extern "C" void kernel_launch(void* const* d_in, const int* in_sizes, int n_in,
                              void* d_out, int out_size, void* d_ws, size_t ws_size,
                              hipStream_t stream)
{
    const float* x      = (const float*)d_in[0];
    const float* weight = (const float*)d_in[1];
    const int* node_in = (const int*)d_in[2];
    const int* top     = (const int*)d_in[3];
    const int* bottom  = (const int*)d_in[4];
    const int* left    = (const int*)d_in[5];
    const int* right   = (const int*)d_in[6];

    float* fws  = (float*)d_ws;                        // 16 slabs x 1.28 MB = 20.5 MB
    int*   cnt  = (int*)(fws + (size_t)CHUNKS * SLAB); // 1 int
    int*   list = cnt + 1;                             // up to 10000 ids
    float* out  = (float*)d_out;                       // 256000 f_in + 96 f_b

    dedup_kernel<<<1, 1024, 0, stream>>>(node_in, top, bottom, left, right, cnt, list);

    dim3 grid((TILES + 3) / 4, CHUNKS);                // 157 x 16 (worst case)
    gemm_kernel<<<grid, 256, 0, stream>>>(x, weight, list, cnt, fws);
    gather_kernel<<<251, 256, 0, stream>>>(fws, node_in, top, bottom, left, right, out);
}